// Round 7
// baseline (233.481 us; speedup 1.0000x reference)
//
#include <hip/hip_runtime.h>
#include <math.h>

#define NB 4
#define NM 32
#define CTOT 282
#define EPSV 1e-3f

__constant__ int g_cL[5]   = {192,48,24,12,6};
__constant__ int g_hL[5]   = {2,4,8,16,32};
__constant__ int g_coff[5] = {0,192,240,264,276};
__constant__ int g_zo[5]   = {0,768,1536,3072,6144};
__constant__ int g_po[4]   = {0,4,20,84};

// 48 level-homogeneous d-tiles
__constant__ int t_lo[48] = {0,0,0,0,0,0,0,0,0,0,0,0,0,0,0,0,
                             0,0,0,0,0,0,0,0,0,0,0,0,0,0,0,0,
                             1,1,1,1,1,1,1,1, 2,2,2,2, 3,3, 4,4};
__constant__ int t_d0[48] = {0,6,12,18,24,30,36,42,48,54,60,66,72,78,84,90,
                             96,102,108,114,120,126,132,138,144,150,156,162,168,174,180,186,
                             192,198,204,210,216,222,228,234, 240,246,252,258, 264,270, 276,279};
__constant__ int t_nd[48] = {6,6,6,6,6,6,6,6,6,6,6,6,6,6,6,6,
                             6,6,6,6,6,6,6,6,6,6,6,6,6,6,6,6,
                             6,6,6,6,6,6,6,6, 6,6,6,6, 6,6, 3,3};

// dft sub-block tables (30 per (which,b)): level + channel offset
__constant__ int dft_l[30]  = {0,0,0, 1,1,1, 2,2,2,2,2,2,
                               3,3,3,3,3,3,3,3,3,3,3,3, 4,4,4,4,4,4};
__constant__ int dft_c0[30] = {0,64,128, 0,16,32, 0,4,8,12,16,20,
                               0,1,2,3,4,5,6,7,8,9,10,11, 0,1,2,3,4,5};
__constant__ int dft_nc[30] = {64,64,64, 16,16,16, 4,4,4,4,4,4,
                               1,1,1,1,1,1,1,1,1,1,1,1, 1,1,1,1,1,1};

// workspace layout (float offsets)
#define N_LA     (NM*CTOT*CTOT)
#define OFF_LAT  0
#define OFF_ZRE  (OFF_LAT + N_LA)
#define OFF_ZIM  (OFF_ZRE + NB*12288)
#define OFF_WRE  (OFF_ZIM + NB*12288)
#define OFF_WIM  (OFF_WRE + NB*12288)
#define OFF_LAM  (OFF_WIM + NB*12288)
#define OFF_LAMF (OFF_LAM + NM*1024)
#define OFF_UR   (OFF_LAMF + NM*340)
#define OFF_UI   (OFF_UR + NB*NM*6*340)
#define OFF_VRE  (OFF_UI + NB*NM*6*340)
#define OFF_VIM  (OFF_VRE + NB*NM*12288)
#define OFF_SZZ  (OFF_VIM + NB*NM*12288)
#define OFF_SZW  (OFF_SZZ + NB*NM*NM)
#define OFF_SWW  (OFF_SZW + NB*NM)
#define OFF_CNT  (OFF_SWW + NB)

#define GRAM_BLOCKS (NB*96)

// k_pre bid ranges
#define PRE_LAT   (NM*81)
#define PRE_LAMF  (PRE_LAT + NM)
#define PRE_DFT   (PRE_LAMF + 2*NB*30)
#define PRE_SWW   (PRE_DFT + NB)
#define PRE_ZERO  (PRE_SWW + 17)

// merged: LaT transpose + lamA/lamfold + DFTs + S_ww + SZZ/CNT zeroing
__global__ void __launch_bounds__(256) k_pre(
    const float* z0,const float* z1,const float* z2,const float* z3,const float* z4,
    const float* w0,const float* w1,const float* w2,const float* w3,const float* w4,
    const float* __restrict__ L, const float* __restrict__ lam, float* __restrict__ ws){
  __shared__ float shm[3136];
  int bid = blockIdx.x, t = threadIdx.x;
  if (bid < PRE_LAT){
    float* A  = shm;
    float* Bt = shm + 1056;
    int m = bid/81; int tl = bid%81;
    int d0 = (tl/9)*32, c0 = (tl%9)*32;
    const float* Lm = L + (size_t)m*CTOT*CTOT;
    for (int i=t;i<1024;i+=256){
      int r=i>>5, c=i&31;
      A[r*33+c]  = (c0+r<CTOT && d0+c<CTOT) ? Lm[(c0+r)*CTOT + d0+c] : 0.f;
      Bt[r*33+c] = (d0+r<CTOT && c0+c<CTOT) ? Lm[(d0+r)*CTOT + c0+c] : 0.f;
    }
    __syncthreads();
    float* out = ws + OFF_LAT + (size_t)m*CTOT*CTOT;
    for (int i=t;i<1024;i+=256){
      int r=i>>5, c=i&31;
      if (d0+r<CTOT && c0+c<CTOT)
        out[(size_t)(d0+r)*CTOT + c0+c] = A[c*33+r] - Bt[r*33+c];
    }
    return;
  }
  if (bid < PRE_LAMF){
    float* sA = shm;
    float* f3 = shm + 1024;
    float* f2 = shm + 1280;
    float* f1 = shm + 1344;
    int m = bid - PRE_LAT;
    for (int k=t;k<1024;k+=256){
      int ky=k>>5, kx=k&31;
      int nk = (((32-ky)&31)<<5) | ((32-kx)&31);
      float v = lam[(m<<10)+k] - lam[(m<<10)+nk];
      sA[k]=v;
      ws[OFF_LAM+(m<<10)+k]=v;
    }
    __syncthreads();
    { int s=t; int ky=s>>4, kx=s&15;
      float v = sA[(ky<<5)+kx]+sA[((ky+16)<<5)+kx]+sA[(ky<<5)+kx+16]+sA[((ky+16)<<5)+kx+16];
      f3[s]=v; ws[OFF_LAMF+m*340+84+s]=v; }
    __syncthreads();
    if (t<64){ int ky=t>>3, kx=t&7;
      float v = f3[(ky<<4)+kx]+f3[((ky+8)<<4)+kx]+f3[(ky<<4)+kx+8]+f3[((ky+8)<<4)+kx+8];
      f2[t]=v; ws[OFF_LAMF+m*340+20+t]=v; }
    __syncthreads();
    if (t<16){ int ky=t>>2, kx=t&3;
      float v = f2[(ky<<3)+kx]+f2[((ky+4)<<3)+kx]+f2[(ky<<3)+kx+4]+f2[((ky+4)<<3)+kx+4];
      f1[t]=v; ws[OFF_LAMF+m*340+4+t]=v; }
    __syncthreads();
    if (t<4){ int ky=t>>1, kx=t&1;
      float v = f1[(ky<<2)+kx]+f1[((ky+2)<<2)+kx]+f1[(ky<<2)+kx+2]+f1[((ky+2)<<2)+kx+2];
      ws[OFF_LAMF+m*340+t]=v; }
    return;
  }
  if (bid < PRE_DFT){
    float* sIn = shm;
    float* s1r = shm + 1024;
    float* s1i = shm + 2048;
    float* lc  = shm + 3072;
    float* lsn = shm + 3104;
    int i0 = bid - PRE_LAMF;
    int which = i0 / (NB*30);
    int rem = i0 % (NB*30);
    int b = rem / 30, j = rem % 30;
    int l = dft_l[j], c0 = dft_c0[j], nc = dft_nc[j];
    int h = g_hL[l], n = h*h;
    int elems = nc*n;
    const float* src;
    switch (which*5 + l){
      case 0: src=z0; break; case 1: src=z1; break; case 2: src=z2; break;
      case 3: src=z3; break; case 4: src=z4; break;
      case 5: src=w0; break; case 6: src=w1; break; case 7: src=w2; break;
      case 8: src=w3; break; default: src=w4; break;
    }
    for (int i=t;i<elems;i+=256) sIn[i] = src[(b*g_cL[l] + c0)*n + i];
    if (t<h){
      float ang = -6.2831853071795864f * (float)t / (float)h;
      lc[t] = cosf(ang); lsn[t] = sinf(ang);
    }
    __syncthreads();
    for (int p=t;p<elems;p+=256){
      int p2=p%n, cc=p/n;
      int y=p2/h, kx=p2-y*h;
      float re=0.f, im=0.f;
      for (int x=0;x<h;x++){
        int id = (kx*x)%h;
        float v = sIn[cc*n + y*h + x];
        re += v*lc[id]; im += v*lsn[id];
      }
      s1r[p]=re; s1i[p]=im;
    }
    __syncthreads();
    float scale = which ? 1.0f/(float)h : 1.0f;
    float* outR = ws + (which?OFF_WRE:OFF_ZRE) + b*12288 + g_zo[l] + c0*n;
    float* outI = ws + (which?OFF_WIM:OFF_ZIM) + b*12288 + g_zo[l] + c0*n;
    for (int p=t;p<elems;p+=256){
      int p2=p%n, cc=p/n;
      int ky=p2/h, kx=p2-(p2/h)*h;
      float re=0.f, im=0.f;
      for (int y=0;y<h;y++){
        int id=(ky*y)%h;
        float c=lc[id], s=lsn[id];
        float ar=s1r[cc*n + y*h + kx], ai=s1i[cc*n + y*h + kx];
        re += ar*c - ai*s;
        im += ar*s + ai*c;
      }
      outR[p]=re*scale; outI[p]=im*scale;
    }
    return;
  }
  if (bid < PRE_SWW){
    float* red = shm;
    int b = bid - PRE_DFT;
    const float* ptr[5] = {w0,w1,w2,w3,w4};
    float s = 0.f;
    for (int l=0;l<5;l++){
      int sz = g_cL[l]*g_hL[l]*g_hL[l];
      const float* p = ptr[l] + b*sz;
      for (int i=t;i<sz;i+=256){ float v=p[i]; s += v*v; }
    }
    red[t]=s; __syncthreads();
    for (int o=128;o>0;o>>=1){ if (t<o) red[t]+=red[t+o]; __syncthreads(); }
    if (t==0) ws[OFF_SWW + b] = red[0];
    return;
  }
  // zero SZZ + SZW (+ completion counter, first zero-block only)
  if (bid == PRE_SWW && t == 0) ((unsigned*)(ws + OFF_CNT))[0] = 0u;
  int i = (bid - PRE_SWW)*256 + t;
  if (i < NB*NM*NM + NB*NM) ws[OFF_SZZ + i] = 0.f;
}

// U[b,m,c4,lout,k'] folds of lamA*Z4
__global__ void k_u(float* __restrict__ ws){
  __shared__ float pr[1024], pi[1024], q3r[256],q3i[256],q2r[64],q2i[64],q1r[16],q1i[16];
  int bid = blockIdx.x, t = threadIdx.x;
  int c = bid%6; int m = (bid/6)%NM; int b = bid/(6*NM);
  const float* la = ws+OFF_LAM+(m<<10);
  const float* zr = ws+OFF_ZRE+b*12288+6144+(c<<10);
  const float* zi = ws+OFF_ZIM+b*12288+6144+(c<<10);
  for (int k=t;k<1024;k+=256){ float f=la[k]; pr[k]=f*zr[k]; pi[k]=f*zi[k]; }
  __syncthreads();
  size_t base = (size_t)((b*NM+m)*6+c)*340;
  float* UR = ws+OFF_UR+base; float* UI = ws+OFF_UI+base;
  { int s=t; int ky=s>>4, kx=s&15;
    float r = pr[(ky<<5)+kx]+pr[((ky+16)<<5)+kx]+pr[(ky<<5)+kx+16]+pr[((ky+16)<<5)+kx+16];
    float ii= pi[(ky<<5)+kx]+pi[((ky+16)<<5)+kx]+pi[(ky<<5)+kx+16]+pi[((ky+16)<<5)+kx+16];
    q3r[s]=r; q3i[s]=ii; UR[84+s]=r; UI[84+s]=ii; }
  __syncthreads();
  if (t<64){ int ky=t>>3, kx=t&7;
    float r = q3r[(ky<<4)+kx]+q3r[((ky+8)<<4)+kx]+q3r[(ky<<4)+kx+8]+q3r[((ky+8)<<4)+kx+8];
    float ii= q3i[(ky<<4)+kx]+q3i[((ky+8)<<4)+kx]+q3i[(ky<<4)+kx+8]+q3i[((ky+8)<<4)+kx+8];
    q2r[t]=r; q2i[t]=ii; UR[20+t]=r; UI[20+t]=ii; }
  __syncthreads();
  if (t<16){ int ky=t>>2, kx=t&3;
    float r = q2r[(ky<<3)+kx]+q2r[((ky+4)<<3)+kx]+q2r[(ky<<3)+kx+4]+q2r[((ky+4)<<3)+kx+4];
    float ii= q2i[(ky<<3)+kx]+q2i[((ky+4)<<3)+kx]+q2i[(ky<<3)+kx+4]+q2i[((ky+4)<<3)+kx+4];
    q1r[t]=r; q1i[t]=ii; UR[4+t]=r; UI[4+t]=ii; }
  __syncthreads();
  if (t<4){ int ky=t>>1, kx=t&1;
    float r = q1r[(ky<<2)+kx]+q1r[((ky+2)<<2)+kx]+q1r[(ky<<2)+kx+2]+q1r[((ky+2)<<2)+kx+2];
    float ii= q1i[(ky<<2)+kx]+q1i[((ky+2)<<2)+kx]+q1i[(ky<<2)+kx+2]+q1i[((ky+2)<<2)+kx+2];
    UR[t]=r; UI[t]=ii; }
}

// hot kernel v7: shuffle-reduced phase 1 (batched over d, level2 adjacent-pair map),
// global-U combine, LDS 24.6 KB -> 6 blocks/CU
__global__ void __launch_bounds__(256) k_fold(float* __restrict__ ws){
  __shared__ float smem[6160];
  float* pre   = smem;          // 6x340
  float* pim   = smem + 2040;   // 6x340
  float* sLa   = smem + 4080;   // 6x284 (chain buffers overlay after phase 1)
  float* c64r  = smem + 4080;   // 384
  float* c64i  = smem + 4464;   // 384
  float* c16r  = smem + 4848;   // 96
  float* c16i  = smem + 4944;   // 96
  float* c4r   = smem + 5040;   // 24
  float* c4i   = smem + 5064;   // 24
  float* lamf  = smem + 5784;   // 340
  float* ssla  = smem + 6124;   // 36

  int t = threadIdx.x, bid = blockIdx.x;
  // m-major: same-m blocks adjacent for LaT L2 reuse
  int m    = bid / (NB*48);
  int rem  = bid % (NB*48);
  int b    = rem / 48;
  int tile = rem % 48;
  int lo = t_lo[tile], d0 = t_d0[tile], nd = t_nd[tile];
  int ho = g_hL[lo];
  int nbins = ho*ho;
  const float* zreb = ws + OFF_ZRE + b*12288;
  const float* zimb = ws + OFF_ZIM + b*12288;
  const float* latm = ws + OFF_LAT + (size_t)m*CTOT*CTOT;

  for (int i=t;i<340;i+=256) lamf[i] = ws[OFF_LAMF + m*340 + i];
  for (int i=t;i<nd*282;i+=256){ int d=i/282, c=i-d*282; sLa[d*284+c] = latm[(size_t)(d0+d)*CTOT + c]; }
  if (t<nd*6){ int d=t/6, c=t-d*6; ssla[t] = latm[(size_t)(d0+d)*CTOT + 276 + c]; }

  // task map (all in-wave reductions):
  //  t<64:   level0: kkA=t&3,  chunk=(t>>2)  -> xor {4,8,16,32}, write lane t<4
  //  t<128:  level1: kkA=i&15, chunk=(i>>4)  -> xor {16,32},     write lane i<16
  //  t<256:  level2: kkA=i>>1, chunk=(i&1)   -> xor {1},         write lane (i&1)==0
  int lA, kkA, c0A, nA, offP; bool wrt;
  if (t<64){ lA=0; kkA=t&3; c0A=(t>>2)*12; nA=4; offP=0; wrt=(t<4); }
  else if (t<128){ int i=t-64; lA=1; kkA=i&15; c0A=(i>>4)*12; nA=16; offP=4; wrt=(i<16); }
  else { int i=t-128; lA=2; kkA=i>>1; c0A=(i&1)*12; nA=64; offP=20; wrt=((i&1)==0); }
  float zAr[12], zAi[12], zBr[12], zBi[12];
  {
    const float* zr = zreb + g_zo[lA] + kkA;
    const float* zi = zimb + g_zo[lA] + kkA;
    #pragma unroll
    for (int c=0;c<12;c++){ zAr[c]=zr[(c0A+c)*nA]; zAi[c]=zi[(c0A+c)*nA]; }
    const float* zr3 = zreb + 3072 + t;
    const float* zi3 = zimb + 3072 + t;
    #pragma unroll
    for (int c=0;c<12;c++){ zBr[c]=zr3[c*256]; zBi[c]=zi3[c*256]; }
  }
  __syncthreads();

  // phase 1: per-d partials; La via ds_read_b128; in-wave xor reduction
  int offA = g_coff[lA] + c0A;
  for (int d=0; d<nd; d++){
    const float4* laA = (const float4*)(sLa + d*284 + offA);
    const float4* laB = (const float4*)(sLa + d*284 + 264);
    float4 a0=laA[0], a1=laA[1], a2=laA[2];
    float4 b0=laB[0], b1=laB[1], b2=laB[2];
    float av[12] = {a0.x,a0.y,a0.z,a0.w, a1.x,a1.y,a1.z,a1.w, a2.x,a2.y,a2.z,a2.w};
    float bv[12] = {b0.x,b0.y,b0.z,b0.w, b1.x,b1.y,b1.z,b1.w, b2.x,b2.y,b2.z,b2.w};
    float prA=0.f, piA=0.f, prB=0.f, piB=0.f;
    #pragma unroll
    for (int c=0;c<12;c++){ prA+=av[c]*zAr[c]; piA+=av[c]*zAi[c]; }
    #pragma unroll
    for (int c=0;c<12;c++){ prB+=bv[c]*zBr[c]; piB+=bv[c]*zBi[c]; }
    if (t<64){
      prA += __shfl_xor(prA, 4);  piA += __shfl_xor(piA, 4);
      prA += __shfl_xor(prA, 8);  piA += __shfl_xor(piA, 8);
      prA += __shfl_xor(prA,16);  piA += __shfl_xor(piA,16);
      prA += __shfl_xor(prA,32);  piA += __shfl_xor(piA,32);
    } else if (t<128){
      prA += __shfl_xor(prA,16);  piA += __shfl_xor(piA,16);
      prA += __shfl_xor(prA,32);  piA += __shfl_xor(piA,32);
    } else {
      prA += __shfl_xor(prA, 1);  piA += __shfl_xor(piA, 1);
    }
    if (wrt){ pre[d*340+offP+kkA]=prA; pim[d*340+offP+kkA]=piA; }
    pre[d*340+84+t]=prB; pim[d*340+84+t]=piB;
  }
  __syncthreads();

  float sc = (float)ho/1024.f;
  if (lo==4){
    int dlb = d0 - 276;
    const float* lamA = ws + OFF_LAM + (m<<10);
    float* vRb = ws + OFF_VRE + (size_t)(b*NM+m)*12288 + 6144 + (dlb<<10);
    float* vIb = ws + OFF_VIM + (size_t)(b*NM+m)*12288 + 6144 + (dlb<<10);
    const float* z4r = zreb + 6144;
    const float* z4i = zimb + 6144;
    for (int q=t; q<1024; q+=256){
      int ky=q>>5, kx=q&31;
      int a0=((ky&1)<<1)|(kx&1);
      int a1=4+(((ky&3)<<2)|(kx&3));
      int a2=20+(((ky&7)<<3)|(kx&7));
      int a3=84+(((ky&15)<<4)|(kx&15));
      float zr_[6], zi_[6];
      #pragma unroll
      for (int c=0;c<6;c++){ zr_[c]=z4r[(c<<10)+q]; zi_[c]=z4i[(c<<10)+q]; }
      float lm = lamA[q]*sc;
      for (int d=0; d<nd; d++){
        const float* pd = pre + d*340; const float* qd = pim + d*340;
        float Br = pd[a0]+pd[a1]+pd[a2]+pd[a3];
        float Bi = qd[a0]+qd[a1]+qd[a2]+qd[a3];
        #pragma unroll
        for (int c=0;c<6;c++){ float a=ssla[d*6+c]; Br+=a*zr_[c]; Bi+=a*zi_[c]; }
        vRb[(d<<10)+q] = -lm*Bi;
        vIb[(d<<10)+q] =  lm*Br;
      }
    }
    return;
  }

  // chain c64 (direct from pre), overlaying the dead sLa region
  if (lo<3){
    for (int idx=t; idx<nd*64; idx+=256){
      int d=idx>>6, k2=idx&63, ky=k2>>3, kx=k2&7;
      const float* pd = pre + d*340 + 84; const float* qd = pim + d*340 + 84;
      float r=0.f, ii=0.f;
      #pragma unroll
      for (int jy=0;jy<2;jy++)
        #pragma unroll
        for (int jx=0;jx<2;jx++){
          int a = ((ky+8*jy)<<4) | (kx+8*jx);
          float f = lamf[84+a];
          r += f*pd[a]; ii += f*qd[a];
        }
      if (lo<2){ float f=lamf[20+k2]; r+=f*pre[d*340+20+k2]; ii+=f*pim[d*340+20+k2]; }
      c64r[idx]=r; c64i[idx]=ii;
    }
  }
  __syncthreads();
  if (lo<2){
    for (int idx=t; idx<nd*16; idx+=256){
      int d=idx>>4, k2=idx&15, ky=k2>>2, kx=k2&3, base=d<<6;
      float r = c64r[base+(ky<<3)+kx]+c64r[base+((ky+4)<<3)+kx]+c64r[base+(ky<<3)+kx+4]+c64r[base+((ky+4)<<3)+kx+4];
      float ii= c64i[base+(ky<<3)+kx]+c64i[base+((ky+4)<<3)+kx]+c64i[base+(ky<<3)+kx+4]+c64i[base+((ky+4)<<3)+kx+4];
      if (lo<1){ float f=lamf[4+k2]; r+=f*pre[d*340+4+k2]; ii+=f*pim[d*340+4+k2]; }
      c16r[idx]=r; c16i[idx]=ii;
    }
  }
  __syncthreads();
  if (lo==0 && t<nd*4){
    int d=t>>2, k2=t&3, ky=k2>>1, kx=k2&1, base=d<<4;
    c4r[t]=c16r[base+(ky<<2)+kx]+c16r[base+((ky+2)<<2)+kx]+c16r[base+(ky<<2)+kx+2]+c16r[base+((ky+2)<<2)+kx+2];
    c4i[t]=c16i[base+(ky<<2)+kx]+c16i[base+((ky+2)<<2)+kx]+c16i[base+(ky<<2)+kx+2]+c16i[base+((ky+2)<<2)+kx+2];
  }
  __syncthreads();

  int dlb = d0 - g_coff[lo];
  float* vRb = ws + OFF_VRE + (size_t)(b*NM+m)*12288 + g_zo[lo];
  float* vIb = ws + OFF_VIM + (size_t)(b*NM+m)*12288 + g_zo[lo];
  const float* URg = ws + OFF_UR + (size_t)((b*NM+m)*6)*340 + g_po[lo];
  const float* UIg = ws + OFF_UI + (size_t)((b*NM+m)*6)*340 + g_po[lo];
  for (int idx=t; idx<nd*nbins; idx+=256){
    int d=idx/nbins, bin=idx-d*nbins;
    int ky=bin/ho, kx=bin-ky*ho;
    const float* pd = pre + d*340; const float* qd = pim + d*340;
    float Br = pd[((ky&1)<<1)|(kx&1)], Bi = qd[((ky&1)<<1)|(kx&1)];
    if (lo>=1){ int ix=4+(((ky&3)<<2)|(kx&3)); Br+=pd[ix]; Bi+=qd[ix]; }
    if (lo>=2){ int ix=20+(((ky&7)<<3)|(kx&7)); Br+=pd[ix]; Bi+=qd[ix]; }
    if (lo>=3){ int ix=84+(((ky&15)<<4)|(kx&15)); Br+=pd[ix]; Bi+=qd[ix]; }
    float lf = lamf[g_po[lo]+bin];
    float Vr = lf*Br, Vi = lf*Bi;
    if (lo==2){ Vr+=c64r[(d<<6)+bin]; Vi+=c64i[(d<<6)+bin]; }
    else if (lo==1){ Vr+=c16r[(d<<4)+bin]; Vi+=c16i[(d<<4)+bin]; }
    else if (lo==0){ Vr+=c4r[(d<<2)+bin]; Vi+=c4i[(d<<2)+bin]; }
    #pragma unroll
    for (int c=0;c<6;c++){ float a=ssla[d*6+c]; Vr+=a*URg[c*340+bin]; Vi+=a*UIg[c*340+bin]; }
    int ob = (dlb+d)*nbins + bin;
    vRb[ob] = -sc*Vi;
    vIb[ob] =  sc*Vr;
  }
}

// S_zz gram + S_zw (register-tiled, float4 LDS) with fused finalization:
// the last block to finish runs var/Cholesky/logdet for all 4 batches in lockstep.
__global__ void __launch_bounds__(256) k_gram(float* __restrict__ ws, float* __restrict__ out){
  __shared__ float tile[32*260];
  __shared__ float wv[256];
  __shared__ unsigned sdone;
  int t = threadIdx.x;
  int bid = blockIdx.x;
  int b = bid / 96, ch = bid % 96;
  int half = ch / 48;
  int k0 = (ch % 48) * 256;
  const float* V = ws + (half?OFF_VIM:OFF_VRE);
  const float* W = ws + (half?OFF_WIM:OFF_WRE) + b*12288 + k0;
  for (int i=t;i<32*256;i+=256){
    int r=i>>8, c=i&255;
    tile[r*260+c] = V[(size_t)(b*NM+r)*12288 + k0 + c];
  }
  wv[t] = W[t];
  __syncthreads();
  const float4* tf = (const float4*)tile;
  int n0 = t>>5, mm = t&31;
  float acc0=0.f, acc1=0.f, acc2=0.f, acc3=0.f;
  const float4* rm = tf + mm*65;
  const float4* r0 = tf + n0*65;
  const float4* r1 = tf + (n0+8)*65;
  const float4* r2 = tf + (n0+16)*65;
  const float4* r3 = tf + (n0+24)*65;
  for (int k4=0;k4<64;k4++){
    float4 vm = rm[k4];
    float4 v0 = r0[k4];
    float4 v1 = r1[k4];
    float4 v2 = r2[k4];
    float4 v3 = r3[k4];
    acc0 += v0.x*vm.x + v0.y*vm.y + v0.z*vm.z + v0.w*vm.w;
    acc1 += v1.x*vm.x + v1.y*vm.y + v1.z*vm.z + v1.w*vm.w;
    acc2 += v2.x*vm.x + v2.y*vm.y + v2.z*vm.z + v2.w*vm.w;
    acc3 += v3.x*vm.x + v3.y*vm.y + v3.z*vm.z + v3.w*vm.w;
  }
  float* szz = ws + OFF_SZZ + (b<<10);
  atomicAdd(&szz[(n0<<5) + mm], acc0);
  atomicAdd(&szz[((n0+8)<<5) + mm], acc1);
  atomicAdd(&szz[((n0+16)<<5) + mm], acc2);
  atomicAdd(&szz[((n0+24)<<5) + mm], acc3);
  if (t < 32){
    const float4* rn = tf + t*65;
    const float4* wf = (const float4*)wv;
    float acc=0.f;
    for (int k4=0;k4<64;k4++){
      float4 a = rn[k4]; float4 wq = wf[k4];
      acc += a.x*wq.x + a.y*wq.y + a.z*wq.z + a.w*wq.w;
    }
    atomicAdd(&ws[OFF_SZW + (b<<5) + t], acc);
  }
  __threadfence();
  if (t==0) sdone = atomicAdd((unsigned*)(ws + OFF_CNT), 1u);
  __syncthreads();
  if (sdone != GRAM_BLOCKS-1) return;

  // ---- finalization (last block): 4 batches, one wave each, lockstep ----
  volatile const float* szzv = ws + OFF_SZZ;
  volatile const float* szwv = ws + OFF_SZW;
  float* A = tile;                 // reuse: 4*1056 = 4224 <= 8320
  int bb = t>>6, tt = t&63;        // wave bb handles batch bb
  float* Ab = A + bb*1056;
  // var = max(mean(diag),1e-6): lanes 0..31 hold diag, xor-reduce
  float v = (tt<32) ? szzv[(bb<<10) + tt*33] : 0.f;
  v += __shfl_xor(v,1); v += __shfl_xor(v,2); v += __shfl_xor(v,4);
  v += __shfl_xor(v,8); v += __shfl_xor(v,16);
  float var = fmaxf(__shfl(v,0) / 32.0f, 1e-6f);
  for (int i=tt;i<1024;i+=64){
    int r=i>>5, c=i&31;
    Ab[r*33+c] = szzv[(bb<<10)+i]/var + ((r==c)?EPSV:0.0f);
  }
  __syncthreads();
  for (int j=0;j<32;j++){
    if (tt==0) Ab[j*33+j] = sqrtf(Ab[j*33+j]);
    __syncthreads();
    if (tt>j && tt<32) Ab[tt*33+j] /= Ab[j*33+j];
    __syncthreads();
    if (tt>j && tt<32){
      float lij = Ab[tt*33+j];
      for (int k=j+1;k<=tt;k++) Ab[tt*33+k] -= lij*Ab[k*33+j];
    }
    __syncthreads();
  }
  float ld = (tt<32) ? logf(Ab[tt*33+tt]) : 0.f;
  ld += __shfl_xor(ld,1); ld += __shfl_xor(ld,2); ld += __shfl_xor(ld,4);
  ld += __shfl_xor(ld,8); ld += __shfl_xor(ld,16);
  float s2 = 0.f;
  if (tt<32){ float x = szwv[(bb<<5)+tt]; s2 = x*x; }
  s2 += __shfl_xor(s2,1); s2 += __shfl_xor(s2,2); s2 += __shfl_xor(s2,4);
  s2 += __shfl_xor(s2,8); s2 += __shfl_xor(s2,16);
  if (tt==0){
    float logdet = 2.0f*ld;
    float trace = EPSV*ws[OFF_SWW + bb] + s2/var;
    out[bb] = 0.5f*(logdet - trace);
  }
}

extern "C" void kernel_launch(void* const* d_in, const int* in_sizes, int n_in,
                              void* d_out, int out_size, void* d_ws, size_t ws_size,
                              hipStream_t stream){
  // setup_inputs() dict order is INTERLEAVED: z0,w0,z1,w1,z2,w2,z3,w3,z4,w4,L,lam
  const float* z0 = (const float*)d_in[0];
  const float* w0 = (const float*)d_in[1];
  const float* z1 = (const float*)d_in[2];
  const float* w1 = (const float*)d_in[3];
  const float* z2 = (const float*)d_in[4];
  const float* w2 = (const float*)d_in[5];
  const float* z3 = (const float*)d_in[6];
  const float* w3 = (const float*)d_in[7];
  const float* z4 = (const float*)d_in[8];
  const float* w4 = (const float*)d_in[9];
  const float* L   = (const float*)d_in[10];
  const float* lam = (const float*)d_in[11];
  float* ws = (float*)d_ws;
  float* out = (float*)d_out;

  k_pre<<<PRE_ZERO, 256, 0, stream>>>(z0,z1,z2,z3,z4,w0,w1,w2,w3,w4, L, lam, ws);
  k_u<<<NB*NM*6, 256, 0, stream>>>(ws);
  k_fold<<<NB*NM*48, 256, 0, stream>>>(ws);
  k_gram<<<GRAM_BLOCKS, 256, 0, stream>>>(ws, out);
}

// Round 8
// 205.979 us; speedup vs baseline: 1.1335x; 1.1335x over previous
//
#include <hip/hip_runtime.h>
#include <math.h>

#define NB 4
#define NM 32
#define CTOT 282
#define EPSV 1e-3f

__constant__ int g_cL[5]   = {192,48,24,12,6};
__constant__ int g_hL[5]   = {2,4,8,16,32};
__constant__ int g_coff[5] = {0,192,240,264,276};
__constant__ int g_zo[5]   = {0,768,1536,3072,6144};
__constant__ int g_po[4]   = {0,4,20,84};

// 48 level-homogeneous d-tiles
__constant__ int t_lo[48] = {0,0,0,0,0,0,0,0,0,0,0,0,0,0,0,0,
                             0,0,0,0,0,0,0,0,0,0,0,0,0,0,0,0,
                             1,1,1,1,1,1,1,1, 2,2,2,2, 3,3, 4,4};
__constant__ int t_d0[48] = {0,6,12,18,24,30,36,42,48,54,60,66,72,78,84,90,
                             96,102,108,114,120,126,132,138,144,150,156,162,168,174,180,186,
                             192,198,204,210,216,222,228,234, 240,246,252,258, 264,270, 276,279};
__constant__ int t_nd[48] = {6,6,6,6,6,6,6,6,6,6,6,6,6,6,6,6,
                             6,6,6,6,6,6,6,6,6,6,6,6,6,6,6,6,
                             6,6,6,6,6,6,6,6, 6,6,6,6, 6,6, 3,3};

// dft sub-block tables (30 per (which,b)): level + channel offset
__constant__ int dft_l[30]  = {0,0,0, 1,1,1, 2,2,2,2,2,2,
                               3,3,3,3,3,3,3,3,3,3,3,3, 4,4,4,4,4,4};
__constant__ int dft_c0[30] = {0,64,128, 0,16,32, 0,4,8,12,16,20,
                               0,1,2,3,4,5,6,7,8,9,10,11, 0,1,2,3,4,5};
__constant__ int dft_nc[30] = {64,64,64, 16,16,16, 4,4,4,4,4,4,
                               1,1,1,1,1,1,1,1,1,1,1,1, 1,1,1,1,1,1};

// workspace layout (float offsets)
#define N_LA     (NM*CTOT*CTOT)
#define OFF_LAT  0
#define OFF_ZRE  (OFF_LAT + N_LA)
#define OFF_ZIM  (OFF_ZRE + NB*12288)
#define OFF_WRE  (OFF_ZIM + NB*12288)
#define OFF_WIM  (OFF_WRE + NB*12288)
#define OFF_LAM  (OFF_WIM + NB*12288)
#define OFF_LAMF (OFF_LAM + NM*1024)
#define OFF_UR   (OFF_LAMF + NM*340)
#define OFF_UI   (OFF_UR + NB*NM*6*340)
#define OFF_VRE  (OFF_UI + NB*NM*6*340)
#define OFF_VIM  (OFF_VRE + NB*NM*12288)
#define OFF_SZZ  (OFF_VIM + NB*NM*12288)
#define OFF_SZW  (OFF_SZZ + NB*NM*NM)
#define OFF_SWW  (OFF_SZW + NB*NM)

// k_pre bid ranges
#define PRE_LAT   (NM*81)
#define PRE_LAMF  (PRE_LAT + NM)
#define PRE_DFT   (PRE_LAMF + 2*NB*30)
#define PRE_SWW   (PRE_DFT + NB)
#define PRE_ZERO  (PRE_SWW + 17)

// merged: LaT transpose + lamA/lamfold + DFTs + S_ww + SZZ zeroing
__global__ void __launch_bounds__(256) k_pre(
    const float* z0,const float* z1,const float* z2,const float* z3,const float* z4,
    const float* w0,const float* w1,const float* w2,const float* w3,const float* w4,
    const float* __restrict__ L, const float* __restrict__ lam, float* __restrict__ ws){
  __shared__ float shm[3136];
  int bid = blockIdx.x, t = threadIdx.x;
  if (bid < PRE_LAT){
    float* A  = shm;
    float* Bt = shm + 1056;
    int m = bid/81; int tl = bid%81;
    int d0 = (tl/9)*32, c0 = (tl%9)*32;
    const float* Lm = L + (size_t)m*CTOT*CTOT;
    for (int i=t;i<1024;i+=256){
      int r=i>>5, c=i&31;
      A[r*33+c]  = (c0+r<CTOT && d0+c<CTOT) ? Lm[(c0+r)*CTOT + d0+c] : 0.f;
      Bt[r*33+c] = (d0+r<CTOT && c0+c<CTOT) ? Lm[(d0+r)*CTOT + c0+c] : 0.f;
    }
    __syncthreads();
    float* out = ws + OFF_LAT + (size_t)m*CTOT*CTOT;
    for (int i=t;i<1024;i+=256){
      int r=i>>5, c=i&31;
      if (d0+r<CTOT && c0+c<CTOT)
        out[(size_t)(d0+r)*CTOT + c0+c] = A[c*33+r] - Bt[r*33+c];
    }
    return;
  }
  if (bid < PRE_LAMF){
    float* sA = shm;
    float* f3 = shm + 1024;
    float* f2 = shm + 1280;
    float* f1 = shm + 1344;
    int m = bid - PRE_LAT;
    for (int k=t;k<1024;k+=256){
      int ky=k>>5, kx=k&31;
      int nk = (((32-ky)&31)<<5) | ((32-kx)&31);
      float v = lam[(m<<10)+k] - lam[(m<<10)+nk];
      sA[k]=v;
      ws[OFF_LAM+(m<<10)+k]=v;
    }
    __syncthreads();
    { int s=t; int ky=s>>4, kx=s&15;
      float v = sA[(ky<<5)+kx]+sA[((ky+16)<<5)+kx]+sA[(ky<<5)+kx+16]+sA[((ky+16)<<5)+kx+16];
      f3[s]=v; ws[OFF_LAMF+m*340+84+s]=v; }
    __syncthreads();
    if (t<64){ int ky=t>>3, kx=t&7;
      float v = f3[(ky<<4)+kx]+f3[((ky+8)<<4)+kx]+f3[(ky<<4)+kx+8]+f3[((ky+8)<<4)+kx+8];
      f2[t]=v; ws[OFF_LAMF+m*340+20+t]=v; }
    __syncthreads();
    if (t<16){ int ky=t>>2, kx=t&3;
      float v = f2[(ky<<3)+kx]+f2[((ky+4)<<3)+kx]+f2[(ky<<3)+kx+4]+f2[((ky+4)<<3)+kx+4];
      f1[t]=v; ws[OFF_LAMF+m*340+4+t]=v; }
    __syncthreads();
    if (t<4){ int ky=t>>1, kx=t&1;
      float v = f1[(ky<<2)+kx]+f1[((ky+2)<<2)+kx]+f1[(ky<<2)+kx+2]+f1[((ky+2)<<2)+kx+2];
      ws[OFF_LAMF+m*340+t]=v; }
    return;
  }
  if (bid < PRE_DFT){
    float* sIn = shm;
    float* s1r = shm + 1024;
    float* s1i = shm + 2048;
    float* lc  = shm + 3072;
    float* lsn = shm + 3104;
    int i0 = bid - PRE_LAMF;
    int which = i0 / (NB*30);
    int rem = i0 % (NB*30);
    int b = rem / 30, j = rem % 30;
    int l = dft_l[j], c0 = dft_c0[j], nc = dft_nc[j];
    int h = g_hL[l], n = h*h;
    int elems = nc*n;
    const float* src;
    switch (which*5 + l){
      case 0: src=z0; break; case 1: src=z1; break; case 2: src=z2; break;
      case 3: src=z3; break; case 4: src=z4; break;
      case 5: src=w0; break; case 6: src=w1; break; case 7: src=w2; break;
      case 8: src=w3; break; default: src=w4; break;
    }
    for (int i=t;i<elems;i+=256) sIn[i] = src[(b*g_cL[l] + c0)*n + i];
    if (t<h){
      float ang = -6.2831853071795864f * (float)t / (float)h;
      lc[t] = cosf(ang); lsn[t] = sinf(ang);
    }
    __syncthreads();
    for (int p=t;p<elems;p+=256){
      int p2=p%n, cc=p/n;
      int y=p2/h, kx=p2-y*h;
      float re=0.f, im=0.f;
      for (int x=0;x<h;x++){
        int id = (kx*x)%h;
        float v = sIn[cc*n + y*h + x];
        re += v*lc[id]; im += v*lsn[id];
      }
      s1r[p]=re; s1i[p]=im;
    }
    __syncthreads();
    float scale = which ? 1.0f/(float)h : 1.0f;
    float* outR = ws + (which?OFF_WRE:OFF_ZRE) + b*12288 + g_zo[l] + c0*n;
    float* outI = ws + (which?OFF_WIM:OFF_ZIM) + b*12288 + g_zo[l] + c0*n;
    for (int p=t;p<elems;p+=256){
      int p2=p%n, cc=p/n;
      int ky=p2/h, kx=p2-(p2/h)*h;
      float re=0.f, im=0.f;
      for (int y=0;y<h;y++){
        int id=(ky*y)%h;
        float c=lc[id], s=lsn[id];
        float ar=s1r[cc*n + y*h + kx], ai=s1i[cc*n + y*h + kx];
        re += ar*c - ai*s;
        im += ar*s + ai*c;
      }
      outR[p]=re*scale; outI[p]=im*scale;
    }
    return;
  }
  if (bid < PRE_SWW){
    float* red = shm;
    int b = bid - PRE_DFT;
    const float* ptr[5] = {w0,w1,w2,w3,w4};
    float s = 0.f;
    for (int l=0;l<5;l++){
      int sz = g_cL[l]*g_hL[l]*g_hL[l];
      const float* p = ptr[l] + b*sz;
      for (int i=t;i<sz;i+=256){ float v=p[i]; s += v*v; }
    }
    red[t]=s; __syncthreads();
    for (int o=128;o>0;o>>=1){ if (t<o) red[t]+=red[t+o]; __syncthreads(); }
    if (t==0) ws[OFF_SWW + b] = red[0];
    return;
  }
  int i = (bid - PRE_SWW)*256 + t;
  if (i < NB*NM*NM + NB*NM) ws[OFF_SZZ + i] = 0.f;
}

// U[b,m,c4,lout,k'] folds of lamA*Z4
__global__ void k_u(float* __restrict__ ws){
  __shared__ float pr[1024], pi[1024], q3r[256],q3i[256],q2r[64],q2i[64],q1r[16],q1i[16];
  int bid = blockIdx.x, t = threadIdx.x;
  int c = bid%6; int m = (bid/6)%NM; int b = bid/(6*NM);
  const float* la = ws+OFF_LAM+(m<<10);
  const float* zr = ws+OFF_ZRE+b*12288+6144+(c<<10);
  const float* zi = ws+OFF_ZIM+b*12288+6144+(c<<10);
  for (int k=t;k<1024;k+=256){ float f=la[k]; pr[k]=f*zr[k]; pi[k]=f*zi[k]; }
  __syncthreads();
  size_t base = (size_t)((b*NM+m)*6+c)*340;
  float* UR = ws+OFF_UR+base; float* UI = ws+OFF_UI+base;
  { int s=t; int ky=s>>4, kx=s&15;
    float r = pr[(ky<<5)+kx]+pr[((ky+16)<<5)+kx]+pr[(ky<<5)+kx+16]+pr[((ky+16)<<5)+kx+16];
    float ii= pi[(ky<<5)+kx]+pi[((ky+16)<<5)+kx]+pi[(ky<<5)+kx+16]+pi[((ky+16)<<5)+kx+16];
    q3r[s]=r; q3i[s]=ii; UR[84+s]=r; UI[84+s]=ii; }
  __syncthreads();
  if (t<64){ int ky=t>>3, kx=t&7;
    float r = q3r[(ky<<4)+kx]+q3r[((ky+8)<<4)+kx]+q3r[(ky<<4)+kx+8]+q3r[((ky+8)<<4)+kx+8];
    float ii= q3i[(ky<<4)+kx]+q3i[((ky+8)<<4)+kx]+q3i[(ky<<4)+kx+8]+q3i[((ky+8)<<4)+kx+8];
    q2r[t]=r; q2i[t]=ii; UR[20+t]=r; UI[20+t]=ii; }
  __syncthreads();
  if (t<16){ int ky=t>>2, kx=t&3;
    float r = q2r[(ky<<3)+kx]+q2r[((ky+4)<<3)+kx]+q2r[(ky<<3)+kx+4]+q2r[((ky+4)<<3)+kx+4];
    float ii= q2i[(ky<<3)+kx]+q2i[((ky+4)<<3)+kx]+q2i[(ky<<3)+kx+4]+q2i[((ky+4)<<3)+kx+4];
    q1r[t]=r; q1i[t]=ii; UR[4+t]=r; UI[4+t]=ii; }
  __syncthreads();
  if (t<4){ int ky=t>>1, kx=t&1;
    float r = q1r[(ky<<2)+kx]+q1r[((ky+2)<<2)+kx]+q1r[(ky<<2)+kx+2]+q1r[((ky+2)<<2)+kx+2];
    float ii= q1i[(ky<<2)+kx]+q1i[((ky+2)<<2)+kx]+q1i[(ky<<2)+kx+2]+q1i[((ky+2)<<2)+kx+2];
    UR[t]=r; UI[t]=ii; }
}

// hot kernel v7: shuffle-reduced phase 1 (in-wave only), global-U combine, 24.6 KB LDS
__global__ void __launch_bounds__(256) k_fold(float* __restrict__ ws){
  __shared__ float smem[6160];
  float* pre   = smem;          // 6x340
  float* pim   = smem + 2040;   // 6x340
  float* sLa   = smem + 4080;   // 6x284 (chain buffers overlay after phase 1)
  float* c64r  = smem + 4080;   // 384
  float* c64i  = smem + 4464;   // 384
  float* c16r  = smem + 4848;   // 96
  float* c16i  = smem + 4944;   // 96
  float* c4r   = smem + 5040;   // 24
  float* c4i   = smem + 5064;   // 24
  float* lamf  = smem + 5784;   // 340
  float* ssla  = smem + 6124;   // 36

  int t = threadIdx.x, bid = blockIdx.x;
  int m    = bid / (NB*48);
  int rem  = bid % (NB*48);
  int b    = rem / 48;
  int tile = rem % 48;
  int lo = t_lo[tile], d0 = t_d0[tile], nd = t_nd[tile];
  int ho = g_hL[lo];
  int nbins = ho*ho;
  const float* zreb = ws + OFF_ZRE + b*12288;
  const float* zimb = ws + OFF_ZIM + b*12288;
  const float* latm = ws + OFF_LAT + (size_t)m*CTOT*CTOT;

  for (int i=t;i<340;i+=256) lamf[i] = ws[OFF_LAMF + m*340 + i];
  for (int i=t;i<nd*282;i+=256){ int d=i/282, c=i-d*282; sLa[d*284+c] = latm[(size_t)(d0+d)*CTOT + c]; }
  if (t<nd*6){ int d=t/6, c=t-d*6; ssla[t] = latm[(size_t)(d0+d)*CTOT + 276 + c]; }

  int lA, kkA, c0A, nA, offP; bool wrt;
  if (t<64){ lA=0; kkA=t&3; c0A=(t>>2)*12; nA=4; offP=0; wrt=(t<4); }
  else if (t<128){ int i=t-64; lA=1; kkA=i&15; c0A=(i>>4)*12; nA=16; offP=4; wrt=(i<16); }
  else { int i=t-128; lA=2; kkA=i>>1; c0A=(i&1)*12; nA=64; offP=20; wrt=((i&1)==0); }
  float zAr[12], zAi[12], zBr[12], zBi[12];
  {
    const float* zr = zreb + g_zo[lA] + kkA;
    const float* zi = zimb + g_zo[lA] + kkA;
    #pragma unroll
    for (int c=0;c<12;c++){ zAr[c]=zr[(c0A+c)*nA]; zAi[c]=zi[(c0A+c)*nA]; }
    const float* zr3 = zreb + 3072 + t;
    const float* zi3 = zimb + 3072 + t;
    #pragma unroll
    for (int c=0;c<12;c++){ zBr[c]=zr3[c*256]; zBi[c]=zi3[c*256]; }
  }
  __syncthreads();

  int offA = g_coff[lA] + c0A;
  for (int d=0; d<nd; d++){
    const float4* laA = (const float4*)(sLa + d*284 + offA);
    const float4* laB = (const float4*)(sLa + d*284 + 264);
    float4 a0=laA[0], a1=laA[1], a2=laA[2];
    float4 b0=laB[0], b1=laB[1], b2=laB[2];
    float av[12] = {a0.x,a0.y,a0.z,a0.w, a1.x,a1.y,a1.z,a1.w, a2.x,a2.y,a2.z,a2.w};
    float bv[12] = {b0.x,b0.y,b0.z,b0.w, b1.x,b1.y,b1.z,b1.w, b2.x,b2.y,b2.z,b2.w};
    float prA=0.f, piA=0.f, prB=0.f, piB=0.f;
    #pragma unroll
    for (int c=0;c<12;c++){ prA+=av[c]*zAr[c]; piA+=av[c]*zAi[c]; }
    #pragma unroll
    for (int c=0;c<12;c++){ prB+=bv[c]*zBr[c]; piB+=bv[c]*zBi[c]; }
    if (t<64){
      prA += __shfl_xor(prA, 4);  piA += __shfl_xor(piA, 4);
      prA += __shfl_xor(prA, 8);  piA += __shfl_xor(piA, 8);
      prA += __shfl_xor(prA,16);  piA += __shfl_xor(piA,16);
      prA += __shfl_xor(prA,32);  piA += __shfl_xor(piA,32);
    } else if (t<128){
      prA += __shfl_xor(prA,16);  piA += __shfl_xor(piA,16);
      prA += __shfl_xor(prA,32);  piA += __shfl_xor(piA,32);
    } else {
      prA += __shfl_xor(prA, 1);  piA += __shfl_xor(piA, 1);
    }
    if (wrt){ pre[d*340+offP+kkA]=prA; pim[d*340+offP+kkA]=piA; }
    pre[d*340+84+t]=prB; pim[d*340+84+t]=piB;
  }
  __syncthreads();

  float sc = (float)ho/1024.f;
  if (lo==4){
    int dlb = d0 - 276;
    const float* lamA = ws + OFF_LAM + (m<<10);
    float* vRb = ws + OFF_VRE + (size_t)(b*NM+m)*12288 + 6144 + (dlb<<10);
    float* vIb = ws + OFF_VIM + (size_t)(b*NM+m)*12288 + 6144 + (dlb<<10);
    const float* z4r = zreb + 6144;
    const float* z4i = zimb + 6144;
    for (int q=t; q<1024; q+=256){
      int ky=q>>5, kx=q&31;
      int a0=((ky&1)<<1)|(kx&1);
      int a1=4+(((ky&3)<<2)|(kx&3));
      int a2=20+(((ky&7)<<3)|(kx&7));
      int a3=84+(((ky&15)<<4)|(kx&15));
      float zr_[6], zi_[6];
      #pragma unroll
      for (int c=0;c<6;c++){ zr_[c]=z4r[(c<<10)+q]; zi_[c]=z4i[(c<<10)+q]; }
      float lm = lamA[q]*sc;
      for (int d=0; d<nd; d++){
        const float* pd = pre + d*340; const float* qd = pim + d*340;
        float Br = pd[a0]+pd[a1]+pd[a2]+pd[a3];
        float Bi = qd[a0]+qd[a1]+qd[a2]+qd[a3];
        #pragma unroll
        for (int c=0;c<6;c++){ float a=ssla[d*6+c]; Br+=a*zr_[c]; Bi+=a*zi_[c]; }
        vRb[(d<<10)+q] = -lm*Bi;
        vIb[(d<<10)+q] =  lm*Br;
      }
    }
    return;
  }

  if (lo<3){
    for (int idx=t; idx<nd*64; idx+=256){
      int d=idx>>6, k2=idx&63, ky=k2>>3, kx=k2&7;
      const float* pd = pre + d*340 + 84; const float* qd = pim + d*340 + 84;
      float r=0.f, ii=0.f;
      #pragma unroll
      for (int jy=0;jy<2;jy++)
        #pragma unroll
        for (int jx=0;jx<2;jx++){
          int a = ((ky+8*jy)<<4) | (kx+8*jx);
          float f = lamf[84+a];
          r += f*pd[a]; ii += f*qd[a];
        }
      if (lo<2){ float f=lamf[20+k2]; r+=f*pre[d*340+20+k2]; ii+=f*pim[d*340+20+k2]; }
      c64r[idx]=r; c64i[idx]=ii;
    }
  }
  __syncthreads();
  if (lo<2){
    for (int idx=t; idx<nd*16; idx+=256){
      int d=idx>>4, k2=idx&15, ky=k2>>2, kx=k2&3, base=d<<6;
      float r = c64r[base+(ky<<3)+kx]+c64r[base+((ky+4)<<3)+kx]+c64r[base+(ky<<3)+kx+4]+c64r[base+((ky+4)<<3)+kx+4];
      float ii= c64i[base+(ky<<3)+kx]+c64i[base+((ky+4)<<3)+kx]+c64i[base+(ky<<3)+kx+4]+c64i[base+((ky+4)<<3)+kx+4];
      if (lo<1){ float f=lamf[4+k2]; r+=f*pre[d*340+4+k2]; ii+=f*pim[d*340+4+k2]; }
      c16r[idx]=r; c16i[idx]=ii;
    }
  }
  __syncthreads();
  if (lo==0 && t<nd*4){
    int d=t>>2, k2=t&3, ky=k2>>1, kx=k2&1, base=d<<4;
    c4r[t]=c16r[base+(ky<<2)+kx]+c16r[base+((ky+2)<<2)+kx]+c16r[base+(ky<<2)+kx+2]+c16r[base+((ky+2)<<2)+kx+2];
    c4i[t]=c16i[base+(ky<<2)+kx]+c16i[base+((ky+2)<<2)+kx]+c16i[base+(ky<<2)+kx+2]+c16i[base+((ky+2)<<2)+kx+2];
  }
  __syncthreads();

  int dlb = d0 - g_coff[lo];
  float* vRb = ws + OFF_VRE + (size_t)(b*NM+m)*12288 + g_zo[lo];
  float* vIb = ws + OFF_VIM + (size_t)(b*NM+m)*12288 + g_zo[lo];
  const float* URg = ws + OFF_UR + (size_t)((b*NM+m)*6)*340 + g_po[lo];
  const float* UIg = ws + OFF_UI + (size_t)((b*NM+m)*6)*340 + g_po[lo];
  for (int idx=t; idx<nd*nbins; idx+=256){
    int d=idx/nbins, bin=idx-d*nbins;
    int ky=bin/ho, kx=bin-ky*ho;
    const float* pd = pre + d*340; const float* qd = pim + d*340;
    float Br = pd[((ky&1)<<1)|(kx&1)], Bi = qd[((ky&1)<<1)|(kx&1)];
    if (lo>=1){ int ix=4+(((ky&3)<<2)|(kx&3)); Br+=pd[ix]; Bi+=qd[ix]; }
    if (lo>=2){ int ix=20+(((ky&7)<<3)|(kx&7)); Br+=pd[ix]; Bi+=qd[ix]; }
    if (lo>=3){ int ix=84+(((ky&15)<<4)|(kx&15)); Br+=pd[ix]; Bi+=qd[ix]; }
    float lf = lamf[g_po[lo]+bin];
    float Vr = lf*Br, Vi = lf*Bi;
    if (lo==2){ Vr+=c64r[(d<<6)+bin]; Vi+=c64i[(d<<6)+bin]; }
    else if (lo==1){ Vr+=c16r[(d<<4)+bin]; Vi+=c16i[(d<<4)+bin]; }
    else if (lo==0){ Vr+=c4r[(d<<2)+bin]; Vi+=c4i[(d<<2)+bin]; }
    #pragma unroll
    for (int c=0;c<6;c++){ float a=ssla[d*6+c]; Vr+=a*URg[c*340+bin]; Vi+=a*UIg[c*340+bin]; }
    int ob = (dlb+d)*nbins + bin;
    vRb[ob] = -sc*Vi;
    vIb[ob] =  sc*Vr;
  }
}

// S_zz gram + S_zw v3: 128-wide k-chunks (768 blocks, 3/CU), float4 global loads,
// register-tiled 4 outputs/thread, float4 LDS reads. No fence, no finalization.
__global__ void __launch_bounds__(256) k_gram(float* __restrict__ ws){
  __shared__ float tile[32*132];   // row stride 132 floats = 33 float4
  __shared__ float wv[128];
  int t = threadIdx.x;
  int bid = blockIdx.x;
  int b = bid / 192, ch = bid % 192;
  int half = ch / 96;
  int k0 = (ch % 96) * 128;
  const float* V = ws + (half?OFF_VIM:OFF_VRE);
  const float* W = ws + (half?OFF_WIM:OFF_WRE) + b*12288 + k0;
  // tile load: 1024 float4s, 4 per thread, coalesced
  #pragma unroll
  for (int p=0;p<4;p++){
    int i4 = t + (p<<8);
    int row = i4 >> 5, c4 = i4 & 31;
    float4 v = *(const float4*)(V + (size_t)(b*NM+row)*12288 + k0 + (c4<<2));
    *(float4*)(tile + row*132 + (c4<<2)) = v;
  }
  if (t<128) wv[t] = W[t];
  __syncthreads();
  const float4* tf = (const float4*)tile;
  int n0 = t>>5, mm = t&31;
  float acc0=0.f, acc1=0.f, acc2=0.f, acc3=0.f;
  const float4* rm = tf + mm*33;
  const float4* r0 = tf + n0*33;
  const float4* r1 = tf + (n0+8)*33;
  const float4* r2 = tf + (n0+16)*33;
  const float4* r3 = tf + (n0+24)*33;
  for (int k4=0;k4<32;k4++){
    float4 vm = rm[k4];
    float4 v0 = r0[k4];
    float4 v1 = r1[k4];
    float4 v2 = r2[k4];
    float4 v3 = r3[k4];
    acc0 += v0.x*vm.x + v0.y*vm.y + v0.z*vm.z + v0.w*vm.w;
    acc1 += v1.x*vm.x + v1.y*vm.y + v1.z*vm.z + v1.w*vm.w;
    acc2 += v2.x*vm.x + v2.y*vm.y + v2.z*vm.z + v2.w*vm.w;
    acc3 += v3.x*vm.x + v3.y*vm.y + v3.z*vm.z + v3.w*vm.w;
  }
  float* szz = ws + OFF_SZZ + (b<<10);
  atomicAdd(&szz[(n0<<5) + mm], acc0);
  atomicAdd(&szz[((n0+8)<<5) + mm], acc1);
  atomicAdd(&szz[((n0+16)<<5) + mm], acc2);
  atomicAdd(&szz[((n0+24)<<5) + mm], acc3);
  if (t < 32){
    const float4* rn = tf + t*33;
    const float4* wf = (const float4*)wv;
    float acc=0.f;
    for (int k4=0;k4<32;k4++){
      float4 a = rn[k4]; float4 wq = wf[k4];
      acc += a.x*wq.x + a.y*wq.y + a.z*wq.z + a.w*wq.w;
    }
    atomicAdd(&ws[OFF_SZW + (b<<5) + t], acc);
  }
}

// var, normalize, Cholesky 32x32 in LDS, logdet, trace, output
__global__ void k_final(float* __restrict__ ws, float* __restrict__ out){
  __shared__ float A[32][33];
  __shared__ float svar;
  int b = blockIdx.x, t = threadIdx.x;
  const float* szz = ws + OFF_SZZ + (b<<10);
  if (t==0){
    float s=0.f;
    for (int i=0;i<32;i++) s += szz[i*33];
    svar = fmaxf(s/32.0f, 1e-6f);
  }
  __syncthreads();
  float var = svar;
  for (int i=t;i<1024;i+=64){
    int r=i>>5, c=i&31;
    A[r][c] = szz[i]/var + ((r==c)?EPSV:0.0f);
  }
  __syncthreads();
  for (int j=0;j<32;j++){
    if (t==0) A[j][j] = sqrtf(A[j][j]);
    __syncthreads();
    if (t>j && t<32) A[t][j] /= A[j][j];
    __syncthreads();
    if (t>j && t<32){
      float lij = A[t][j];
      for (int k=j+1;k<=t;k++) A[t][k] -= lij*A[k][j];
    }
    __syncthreads();
  }
  if (t==0){
    float logdet=0.f;
    for (int j=0;j<32;j++) logdet += logf(A[j][j]);
    logdet *= 2.0f;
    const float* szw = ws + OFF_SZW + (b<<5);
    float s2=0.f;
    for (int n=0;n<32;n++) s2 += szw[n]*szw[n];
    float trace = EPSV*ws[OFF_SWW + b] + s2/var;
    out[b] = 0.5f*(logdet - trace);
  }
}

extern "C" void kernel_launch(void* const* d_in, const int* in_sizes, int n_in,
                              void* d_out, int out_size, void* d_ws, size_t ws_size,
                              hipStream_t stream){
  // setup_inputs() dict order is INTERLEAVED: z0,w0,z1,w1,z2,w2,z3,w3,z4,w4,L,lam
  const float* z0 = (const float*)d_in[0];
  const float* w0 = (const float*)d_in[1];
  const float* z1 = (const float*)d_in[2];
  const float* w1 = (const float*)d_in[3];
  const float* z2 = (const float*)d_in[4];
  const float* w2 = (const float*)d_in[5];
  const float* z3 = (const float*)d_in[6];
  const float* w3 = (const float*)d_in[7];
  const float* z4 = (const float*)d_in[8];
  const float* w4 = (const float*)d_in[9];
  const float* L   = (const float*)d_in[10];
  const float* lam = (const float*)d_in[11];
  float* ws = (float*)d_ws;
  float* out = (float*)d_out;

  k_pre<<<PRE_ZERO, 256, 0, stream>>>(z0,z1,z2,z3,z4,w0,w1,w2,w3,w4, L, lam, ws);
  k_u<<<NB*NM*6, 256, 0, stream>>>(ws);
  k_fold<<<NB*NM*48, 256, 0, stream>>>(ws);
  k_gram<<<NB*192, 256, 0, stream>>>(ws);
  k_final<<<NB, 64, 0, stream>>>(ws, out);
}